// Round 1
// baseline (308.187 us; speedup 1.0000x reference)
//
#include <hip/hip_runtime.h>
#include <cstdint>
#include <cstddef>

#define DEV static __device__ __forceinline__

typedef __attribute__((ext_vector_type(8))) short bf16x8;
typedef __attribute__((ext_vector_type(4))) float f32x4;

// fp32 -> bf16 round-to-nearest-even
DEV uint16_t f2bf(float f) {
  uint32_t u = __builtin_bit_cast(uint32_t, f);
  u += 0x7FFFu + ((u >> 16) & 1u);
  return (uint16_t)(u >> 16);
}

// async global->LDS, 16B per lane; LDS dest is wave-uniform base + lane*16
DEV void load_lds16(const void* g, void* l) {
  auto gp = reinterpret_cast<const uint32_t __attribute__((address_space(1)))*>(
      reinterpret_cast<uintptr_t>(g));
  auto lp = reinterpret_cast<uint32_t __attribute__((address_space(3)))*>(
      reinterpret_cast<uintptr_t>(l));
  __builtin_amdgcn_global_load_lds(gp, lp, 16, 0, 0);
}

__global__ __launch_bounds__(256) void cvt_bf16(const float* __restrict__ s,
                                                uint16_t* __restrict__ d, int n) {
  int i = (blockIdx.x * 256 + threadIdx.x) * 4;
  if (i >= n) return;
  float4 v = *reinterpret_cast<const float4*>(s + i);
  ushort4 o;
  o.x = f2bf(v.x); o.y = f2bf(v.y); o.z = f2bf(v.z); o.w = f2bf(v.w);
  *reinterpret_cast<ushort4*>(d + i) = o;
}

enum { EPI_ROPE = 0, EPI_VT = 1, EPI_F32 = 2 };

// C = A * B^T,  A: 4096x1024 bf16 row-major, Bw: 1024x1024 bf16 (N x K).
// 128x128 block tile, BK=64, 4 waves, 64x64 per wave (4x4 of 16x16x32 MFMA).
// LDS rows are 128B (64 bf16); 16B chunks XOR-swizzled by (row&7) -> ~2-way.
template <int EPI>
__global__ __launch_bounds__(256) void gemm_nt(const uint16_t* __restrict__ A,
                                               const uint16_t* __restrict__ Bw,
                                               void* __restrict__ Out,
                                               const int* __restrict__ tokpos) {
  __shared__ union {
    struct { uint16_t a[128 * 64]; uint16_t b[128 * 64]; } st;  // 32 KiB
    uint16_t t[128 * 128];                                      // epilogue transpose
  } sm;

  const int tid = threadIdx.x;
  const int lane = tid & 63, w = tid >> 6;
  const int q = lane >> 4, l16 = lane & 15;
  const int wm = w & 1, wn = w >> 1;
  const int bm = blockIdx.y, bn = blockIdx.x;

  const f32x4 z4 = {0.f, 0.f, 0.f, 0.f};
  f32x4 acc[4][4];
#pragma unroll
  for (int i = 0; i < 4; ++i)
#pragma unroll
    for (int j = 0; j < 4; ++j) acc[i][j] = z4;

  const int srow = tid >> 3, sslot = tid & 7;
  const uint16_t* Ab = A + (size_t)bm * 128 * 1024;
  const uint16_t* Bb = Bw + (size_t)bn * 128 * 1024;

  for (int k0 = 0; k0 < 1024; k0 += 64) {
    __syncthreads();
#pragma unroll
    for (int is = 0; is < 4; ++is) {
      int row = is * 32 + srow;
      int gch = sslot ^ (row & 7);
      char* la = (char*)sm.st.a + (is * 32 + w * 8) * 128;
      char* lb = (char*)sm.st.b + (is * 32 + w * 8) * 128;
      load_lds16(Ab + (size_t)row * 1024 + k0 + gch * 8, la);
      load_lds16(Bb + (size_t)row * 1024 + k0 + gch * 8, lb);
    }
    __syncthreads();
#pragma unroll
    for (int ks = 0; ks < 2; ++ks) {
      bf16x8 af[4], bfr[4];
#pragma unroll
      for (int i = 0; i < 4; ++i) {
        int ra = wm * 64 + i * 16 + l16;
        af[i] = *reinterpret_cast<const bf16x8*>(sm.st.a + ra * 64 +
                                                 (((ks * 4 + q) ^ (ra & 7)) * 8));
        int rb = wn * 64 + i * 16 + l16;
        bfr[i] = *reinterpret_cast<const bf16x8*>(sm.st.b + rb * 64 +
                                                  (((ks * 4 + q) ^ (rb & 7)) * 8));
      }
#pragma unroll
      for (int i = 0; i < 4; ++i)
#pragma unroll
        for (int j = 0; j < 4; ++j)
          acc[i][j] =
              __builtin_amdgcn_mfma_f32_16x16x32_bf16(af[i], bfr[j], acc[i][j], 0, 0, 0);
    }
  }

  // C/D layout: col = lane&15, row = quad*4 + reg  [m89/m91 verified]
  if constexpr (EPI == EPI_ROPE) {
    uint16_t* O = (uint16_t*)Out;
#pragma unroll
    for (int j = 0; j < 4; ++j) {
      int gn = bn * 128 + wn * 64 + j * 16 + l16;
      int dim = gn & 63;
      // freq = theta^(-(2*(dim/2))/64) = exp(-(dim&~1) * ln(1e4)/64)
      float freq = __expf(-0.14391156f * (float)(dim & ~1));
      float sgn = (lane & 1) ? 1.f : -1.f;  // even lane: y=v*c - o*s ; odd: y=o*s + v*c
#pragma unroll
      for (int i = 0; i < 4; ++i) {
#pragma unroll
        for (int r = 0; r < 4; ++r) {
          int gm = bm * 128 + wm * 64 + i * 16 + q * 4 + r;
          float pos = (float)tokpos[gm & 2047];
          float sn, cs;
          __sincosf(pos * freq, &sn, &cs);
          float v = acc[i][j][r];
          float o = __shfl_xor(v, 1);
          O[(size_t)gm * 1024 + gn] = f2bf(v * cs + sgn * o * sn);
        }
      }
    }
  } else if constexpr (EPI == EPI_VT) {
    // write V^T [b,h,d,s] so attention can stage it with global_load_lds
    __syncthreads();
#pragma unroll
    for (int i = 0; i < 4; ++i)
#pragma unroll
      for (int j = 0; j < 4; ++j)
#pragma unroll
        for (int r = 0; r < 4; ++r) {
          int mL = wm * 64 + i * 16 + q * 4 + r;
          int nL = wn * 64 + j * 16 + l16;
          int ch = (mL >> 3) ^ (nL & 15);  // 16B-chunk swizzle, keyed by n
          sm.t[nL * 128 + ch * 8 + (mL & 7)] = f2bf(acc[i][j][r]);
        }
    __syncthreads();
    uint16_t* O = (uint16_t*)Out;
    const int b = (bm * 128) >> 11;
    const int sblk = (bm * 128) & 2047;
#pragma unroll
    for (int it = 0; it < 8; ++it) {
      int nL = it * 16 + (tid >> 4);
      int mch = tid & 15;
      int slot = mch ^ (nL & 15);
      bf16x8 vv = *reinterpret_cast<const bf16x8*>(sm.t + nL * 128 + slot * 8);
      int gn = bn * 128 + nL;
      int h = gn >> 6, d = gn & 63;
      *reinterpret_cast<bf16x8*>(O + ((size_t)((b * 16 + h) * 64 + d)) * 2048 + sblk +
                                 mch * 8) = vv;
    }
  } else {
    float* O = (float*)Out;
#pragma unroll
    for (int i = 0; i < 4; ++i)
#pragma unroll
      for (int r = 0; r < 4; ++r) {
        int gm = bm * 128 + wm * 64 + i * 16 + q * 4 + r;
#pragma unroll
        for (int j = 0; j < 4; ++j) {
          int gn = bn * 128 + wn * 64 + j * 16 + l16;
          O[(size_t)gm * 1024 + gn] = acc[i][j][r];
        }
      }
  }
}

// Flash attention, causal. Q,K: [b,s,h,d] bf16; VT: [b,h,d,s] bf16; AO: [b,s,h,d] bf16.
// Block = (q-tile of 128 rows) x (b,h). 4 waves, 32 q-rows each. K-tiles of 64.
__global__ __launch_bounds__(256) void flash_attn(const uint16_t* __restrict__ Q,
                                                  const uint16_t* __restrict__ K,
                                                  const uint16_t* __restrict__ VT,
                                                  uint16_t* __restrict__ AO) {
  __shared__ uint16_t ksm[64 * 64];     // K-tile, swizzled rows
  __shared__ uint16_t vsm[64 * 64];     // V^T tile (rows = d), swizzled
  __shared__ uint16_t psm[4][32 * 64];  // per-wave P round-trip

  const int tid = threadIdx.x;
  const int lane = tid & 63, w = tid >> 6;
  const int q = lane >> 4, l16 = lane & 15;
  const int qt = 15 - blockIdx.x;  // heavy tiles first
  const int bh = blockIdx.y;
  const int b = bh >> 4, h = bh & 15;

  const size_t baseBS = (size_t)b * 2048 * 1024 + h * 64;
  const size_t baseVT = (size_t)(b * 16 + h) * 64 * 2048;

  // Q fragments kept in registers: A-layout m=lane&15, k=quad*8+j
  bf16x8 qf[2][2];
  const int r0 = qt * 128 + w * 32;
#pragma unroll
  for (int mi = 0; mi < 2; ++mi)
#pragma unroll
    for (int ks = 0; ks < 2; ++ks)
      qf[mi][ks] = *reinterpret_cast<const bf16x8*>(
          Q + baseBS + (size_t)(r0 + mi * 16 + l16) * 1024 + ks * 32 + q * 8);

  const f32x4 z4 = {0.f, 0.f, 0.f, 0.f};
  f32x4 oa[2][4];
#pragma unroll
  for (int mi = 0; mi < 2; ++mi)
#pragma unroll
    for (int di = 0; di < 4; ++di) oa[mi][di] = z4;
  float m_i[2][4], l_i[2][4];
#pragma unroll
  for (int mi = 0; mi < 2; ++mi)
#pragma unroll
    for (int r = 0; r < 4; ++r) { m_i[mi][r] = -1e30f; l_i[mi][r] = 0.f; }

  const int srow = tid >> 3, sslot = tid & 7;
  const int nkt = 2 * qt + 2;

  for (int kt = 0; kt < nkt; ++kt) {
    __syncthreads();  // protect ksm/vsm from prior iteration's readers
#pragma unroll
    for (int is = 0; is < 2; ++is) {
      int row = is * 32 + srow;
      int gch = sslot ^ (row & 7);
      load_lds16(K + baseBS + (size_t)(kt * 64 + row) * 1024 + gch * 8,
                 (char*)ksm + (is * 32 + w * 8) * 128);
      load_lds16(VT + baseVT + (size_t)row * 2048 + kt * 64 + gch * 8,
                 (char*)vsm + (is * 32 + w * 8) * 128);
    }
    __syncthreads();

    // S = Q K^T
    f32x4 sc[2][4];
#pragma unroll
    for (int mi = 0; mi < 2; ++mi)
#pragma unroll
      for (int nj = 0; nj < 4; ++nj) sc[mi][nj] = z4;
#pragma unroll
    for (int ks = 0; ks < 2; ++ks) {
      bf16x8 kf[4];
#pragma unroll
      for (int nj = 0; nj < 4; ++nj) {
        int rk = nj * 16 + l16;
        kf[nj] = *reinterpret_cast<const bf16x8*>(ksm + rk * 64 +
                                                  (((ks * 4 + q) ^ (rk & 7)) * 8));
      }
#pragma unroll
      for (int mi = 0; mi < 2; ++mi)
#pragma unroll
        for (int nj = 0; nj < 4; ++nj)
          sc[mi][nj] =
              __builtin_amdgcn_mfma_f32_16x16x32_bf16(qf[mi][ks], kf[nj], sc[mi][nj], 0, 0, 0);
    }

    // scale + causal mask
    const int rowg0 = qt * 128 + w * 32;
#pragma unroll
    for (int mi = 0; mi < 2; ++mi)
#pragma unroll
      for (int nj = 0; nj < 4; ++nj)
#pragma unroll
        for (int r = 0; r < 4; ++r) {
          int col = kt * 64 + nj * 16 + l16;
          int row = rowg0 + mi * 16 + q * 4 + r;
          float x = sc[mi][nj][r] * 0.125f;
          sc[mi][nj][r] = (col <= row) ? x : -1e30f;
        }

    // online softmax: row max (over nj then 16 lanes of same quad)
    float alpha[2][4], rs[2][4];
#pragma unroll
    for (int mi = 0; mi < 2; ++mi)
#pragma unroll
      for (int r = 0; r < 4; ++r) {
        float v = fmaxf(fmaxf(sc[mi][0][r], sc[mi][1][r]),
                        fmaxf(sc[mi][2][r], sc[mi][3][r]));
        v = fmaxf(v, __shfl_xor(v, 1));
        v = fmaxf(v, __shfl_xor(v, 2));
        v = fmaxf(v, __shfl_xor(v, 4));
        v = fmaxf(v, __shfl_xor(v, 8));
        float mn = fmaxf(m_i[mi][r], v);
        alpha[mi][r] = __expf(m_i[mi][r] - mn);
        m_i[mi][r] = mn;
        rs[mi][r] = 0.f;
      }

    // P = exp(S - m); write to per-wave LDS in A-layout-friendly swizzled form
#pragma unroll
    for (int mi = 0; mi < 2; ++mi)
#pragma unroll
      for (int nj = 0; nj < 4; ++nj)
#pragma unroll
        for (int r = 0; r < 4; ++r) {
          float p = __expf(sc[mi][nj][r] - m_i[mi][r]);
          rs[mi][r] += p;
          int pr = mi * 16 + q * 4 + r;
          int pc = nj * 16 + l16;
          psm[w][pr * 64 + (((pc >> 3) ^ (pr & 7)) * 8) + (pc & 7)] = f2bf(p);
        }

#pragma unroll
    for (int mi = 0; mi < 2; ++mi)
#pragma unroll
      for (int r = 0; r < 4; ++r) {
        float v = rs[mi][r];
        v += __shfl_xor(v, 1);
        v += __shfl_xor(v, 2);
        v += __shfl_xor(v, 4);
        v += __shfl_xor(v, 8);
        l_i[mi][r] = l_i[mi][r] * alpha[mi][r] + v;
      }

#pragma unroll
    for (int mi = 0; mi < 2; ++mi)
#pragma unroll
      for (int di = 0; di < 4; ++di)
#pragma unroll
        for (int r = 0; r < 4; ++r) oa[mi][di][r] *= alpha[mi][r];

    // O += P V   (B-operand rows = d from V^T tile; same-wave LDS RAW, no barrier)
#pragma unroll
    for (int ks = 0; ks < 2; ++ks) {
      bf16x8 pf[2], vf[4];
#pragma unroll
      for (int mi = 0; mi < 2; ++mi) {
        int pr = mi * 16 + l16;
        pf[mi] = *reinterpret_cast<const bf16x8*>(psm[w] + pr * 64 +
                                                  (((ks * 4 + q) ^ (pr & 7)) * 8));
      }
#pragma unroll
      for (int di = 0; di < 4; ++di) {
        int vr = di * 16 + l16;
        vf[di] = *reinterpret_cast<const bf16x8*>(vsm + vr * 64 +
                                                  (((ks * 4 + q) ^ (vr & 7)) * 8));
      }
#pragma unroll
      for (int mi = 0; mi < 2; ++mi)
#pragma unroll
        for (int di = 0; di < 4; ++di)
          oa[mi][di] =
              __builtin_amdgcn_mfma_f32_16x16x32_bf16(pf[mi], vf[di], oa[mi][di], 0, 0, 0);
    }
  }

#pragma unroll
  for (int mi = 0; mi < 2; ++mi)
#pragma unroll
    for (int r = 0; r < 4; ++r) {
      float inv = 1.f / l_i[mi][r];
      int gm = qt * 128 + w * 32 + mi * 16 + q * 4 + r;
#pragma unroll
      for (int di = 0; di < 4; ++di)
        AO[baseBS + (size_t)gm * 1024 + di * 16 + l16] = f2bf(oa[mi][di][r] * inv);
    }
}

extern "C" void kernel_launch(void* const* d_in, const int* in_sizes, int n_in,
                              void* d_out, int out_size, void* d_ws, size_t ws_size,
                              hipStream_t stream) {
  (void)in_sizes; (void)n_in; (void)out_size; (void)ws_size;
  const float* x = (const float*)d_in[0];
  const int* tokpos = (const int*)d_in[1];
  const float* wq = (const float*)d_in[2];
  const float* wk = (const float*)d_in[3];
  const float* wv = (const float*)d_in[4];
  const float* wo = (const float*)d_in[5];
  float* out = (float*)d_out;

  // workspace layout (bf16 elements): 48 MB total
  uint16_t* ws = (uint16_t*)d_ws;
  uint16_t* xb = ws;                   // 4096*1024
  uint16_t* wqb = xb + 4194304;        // 1024*1024 each
  uint16_t* wkb = wqb + 1048576;
  uint16_t* wvb = wkb + 1048576;
  uint16_t* wob = wvb + 1048576;
  uint16_t* Qb = wob + 1048576;        // [b,s,h,d]
  uint16_t* Kb = Qb + 4194304;         // [b,s,h,d]
  uint16_t* VTb = Kb + 4194304;        // [b,h,d,s]
  uint16_t* AOb = VTb + 4194304;       // [b,s,h,d]

  cvt_bf16<<<4096, 256, 0, stream>>>(x, xb, 4194304);
  cvt_bf16<<<1024, 256, 0, stream>>>(wq, wqb, 1048576);
  cvt_bf16<<<1024, 256, 0, stream>>>(wk, wkb, 1048576);
  cvt_bf16<<<1024, 256, 0, stream>>>(wv, wvb, 1048576);
  cvt_bf16<<<1024, 256, 0, stream>>>(wo, wob, 1048576);

  dim3 gg(8, 32);
  gemm_nt<EPI_ROPE><<<gg, 256, 0, stream>>>(xb, wqb, Qb, tokpos);
  gemm_nt<EPI_ROPE><<<gg, 256, 0, stream>>>(xb, wkb, Kb, tokpos);
  gemm_nt<EPI_VT><<<gg, 256, 0, stream>>>(xb, wvb, VTb, nullptr);

  flash_attn<<<dim3(16, 32), 256, 0, stream>>>(Qb, Kb, VTb, AOb);

  gemm_nt<EPI_F32><<<gg, 256, 0, stream>>>(AOb, wob, out, nullptr);
}

// Round 3
// 263.115 us; speedup vs baseline: 1.1713x; 1.1713x over previous
//
#include <hip/hip_runtime.h>
#include <cstdint>
#include <cstddef>

#define DEV static __device__ __forceinline__

typedef __attribute__((ext_vector_type(8))) short bf16x8;
typedef __attribute__((ext_vector_type(4))) float f32x4;

// fp32 -> bf16 round-to-nearest-even
DEV uint16_t f2bf(float f) {
  uint32_t u = __builtin_bit_cast(uint32_t, f);
  u += 0x7FFFu + ((u >> 16) & 1u);
  return (uint16_t)(u >> 16);
}

// native v_exp_f32 (2^x) — avoid __exp2f name clash with glibc math.h
DEV float fexp2(float x) { return __builtin_amdgcn_exp2f(x); }

// async global->LDS, 16B per lane; LDS dest is wave-uniform base + lane*16
DEV void load_lds16(const void* g, void* l) {
  auto gp = reinterpret_cast<const uint32_t __attribute__((address_space(1)))*>(
      reinterpret_cast<uintptr_t>(g));
  auto lp = reinterpret_cast<uint32_t __attribute__((address_space(3)))*>(
      reinterpret_cast<uintptr_t>(l));
  __builtin_amdgcn_global_load_lds(gp, lp, 16, 0, 0);
}

// One fused fp32->bf16 convert for x + the 4 weight matrices.
// dst layout: [x(4M) | wq(1M) | wk(1M) | wv(1M) | wo(1M)] (element counts)
__global__ __launch_bounds__(256) void cvt_all(const float* __restrict__ x,
                                               const float* __restrict__ wq,
                                               const float* __restrict__ wk,
                                               const float* __restrict__ wv,
                                               const float* __restrict__ wo,
                                               uint16_t* __restrict__ dst) {
  int gi = blockIdx.x * 1024 + threadIdx.x * 4;
  const float* s;
  int li;
  if (gi < 4194304) {
    s = x; li = gi;
  } else {
    int j = gi - 4194304;
    int r = j >> 20;
    li = j & 1048575;
    s = (r == 0) ? wq : (r == 1) ? wk : (r == 2) ? wv : wo;
  }
  float4 v = *reinterpret_cast<const float4*>(s + li);
  ushort4 o;
  o.x = f2bf(v.x); o.y = f2bf(v.y); o.z = f2bf(v.z); o.w = f2bf(v.w);
  *reinterpret_cast<ushort4*>(dst + gi) = o;
}

// Fused QKV GEMM: C = A * Wqkv^T, A: 4096x1024, Wqkv: 3072x1024 (wq|wk|wv rows).
// 128x128 tile, BK=64, 4 waves x (64x64). Epilogue by bn>>3: 0,1 -> RoPE (Q/K),
// 2 -> V^T [b,h,d,s]. grid (24, 32) = 768 blocks.
__global__ __launch_bounds__(256) void gemm_qkv(const uint16_t* __restrict__ A,
                                                const uint16_t* __restrict__ Wqkv,
                                                uint16_t* __restrict__ QK,  // Qb; Kb at +4194304
                                                uint16_t* __restrict__ VTb,
                                                const int* __restrict__ tokpos) {
  __shared__ union {
    struct { uint16_t a[128 * 64]; uint16_t b[128 * 64]; } st;  // 32 KiB
    uint16_t t[128 * 128];                                      // epilogue transpose
  } sm;

  const int tid = threadIdx.x;
  const int lane = tid & 63, w = tid >> 6;
  const int q = lane >> 4, l16 = lane & 15;
  const int wm = w & 1, wn = w >> 1;
  const int bm = blockIdx.y, bn = blockIdx.x;
  const int wsel = bn >> 3;

  const f32x4 z4 = {0.f, 0.f, 0.f, 0.f};
  f32x4 acc[4][4];
#pragma unroll
  for (int i = 0; i < 4; ++i)
#pragma unroll
    for (int j = 0; j < 4; ++j) acc[i][j] = z4;

  const int srow = tid >> 3, sslot = tid & 7;
  const uint16_t* Ab = A + (size_t)bm * 128 * 1024;
  const uint16_t* Bb = Wqkv + (size_t)bn * 128 * 1024;

  for (int k0 = 0; k0 < 1024; k0 += 64) {
    __syncthreads();
#pragma unroll
    for (int is = 0; is < 4; ++is) {
      int row = is * 32 + srow;
      int gch = sslot ^ (row & 7);
      char* la = (char*)sm.st.a + (is * 32 + w * 8) * 128;
      char* lb = (char*)sm.st.b + (is * 32 + w * 8) * 128;
      load_lds16(Ab + (size_t)row * 1024 + k0 + gch * 8, la);
      load_lds16(Bb + (size_t)row * 1024 + k0 + gch * 8, lb);
    }
    __syncthreads();
#pragma unroll
    for (int ks = 0; ks < 2; ++ks) {
      bf16x8 af[4], bfr[4];
#pragma unroll
      for (int i = 0; i < 4; ++i) {
        int ra = wm * 64 + i * 16 + l16;
        af[i] = *reinterpret_cast<const bf16x8*>(sm.st.a + ra * 64 +
                                                 (((ks * 4 + q) ^ (ra & 7)) * 8));
        int rb = wn * 64 + i * 16 + l16;
        bfr[i] = *reinterpret_cast<const bf16x8*>(sm.st.b + rb * 64 +
                                                  (((ks * 4 + q) ^ (rb & 7)) * 8));
      }
#pragma unroll
      for (int i = 0; i < 4; ++i)
#pragma unroll
        for (int j = 0; j < 4; ++j)
          acc[i][j] =
              __builtin_amdgcn_mfma_f32_16x16x32_bf16(af[i], bfr[j], acc[i][j], 0, 0, 0);
    }
  }

  // C/D layout: col = lane&15, row = quad*4 + reg  [m89/m91 verified]
  if (wsel < 2) {
    uint16_t* O = QK + (size_t)wsel * 4194304;
#pragma unroll
    for (int j = 0; j < 4; ++j) {
      int gn = bn * 128 + wn * 64 + j * 16 + l16;
      int cn = gn & 1023;
      int dim = gn & 63;
      float freq = __expf(-0.14391156f * (float)(dim & ~1));
      float sgn = (lane & 1) ? 1.f : -1.f;
#pragma unroll
      for (int i = 0; i < 4; ++i) {
#pragma unroll
        for (int r = 0; r < 4; ++r) {
          int gm = bm * 128 + wm * 64 + i * 16 + q * 4 + r;
          float pos = (float)tokpos[gm & 2047];
          float sn, cs;
          __sincosf(pos * freq, &sn, &cs);
          float v = acc[i][j][r];
          float o = __shfl_xor(v, 1);
          O[(size_t)gm * 1024 + cn] = f2bf(v * cs + sgn * o * sn);
        }
      }
    }
  } else {
    // V^T [b,h,d,s]
    const int bnv = bn & 7;
    __syncthreads();
#pragma unroll
    for (int i = 0; i < 4; ++i)
#pragma unroll
      for (int j = 0; j < 4; ++j)
#pragma unroll
        for (int r = 0; r < 4; ++r) {
          int mL = wm * 64 + i * 16 + q * 4 + r;
          int nL = wn * 64 + j * 16 + l16;
          int ch = (mL >> 3) ^ (nL & 15);
          sm.t[nL * 128 + ch * 8 + (mL & 7)] = f2bf(acc[i][j][r]);
        }
    __syncthreads();
    const int b = (bm * 128) >> 11;
    const int sblk = (bm * 128) & 2047;
#pragma unroll
    for (int it = 0; it < 8; ++it) {
      int nL = it * 16 + (tid >> 4);
      int mch = tid & 15;
      int slot = mch ^ (nL & 15);
      bf16x8 vv = *reinterpret_cast<const bf16x8*>(sm.t + nL * 128 + slot * 8);
      int gn = bnv * 128 + nL;
      int h = gn >> 6, d = gn & 63;
      *reinterpret_cast<bf16x8*>(VTb + ((size_t)((b * 16 + h) * 64 + d)) * 2048 + sblk +
                                 mch * 8) = vv;
    }
  }
}

// Output projection: C = A * Wo^T fp32. 128x64 tile -> grid (16, 32) = 512 blocks.
__global__ __launch_bounds__(256) void gemm_out(const uint16_t* __restrict__ A,
                                                const uint16_t* __restrict__ Bw,
                                                float* __restrict__ O) {
  __shared__ uint16_t sa[128 * 64];  // 16 KiB
  __shared__ uint16_t sb[64 * 64];   // 8 KiB

  const int tid = threadIdx.x;
  const int lane = tid & 63, w = tid >> 6;
  const int q = lane >> 4, l16 = lane & 15;
  const int bm = blockIdx.y, bn = blockIdx.x;

  const f32x4 z4 = {0.f, 0.f, 0.f, 0.f};
  f32x4 acc[2][4];
#pragma unroll
  for (int i = 0; i < 2; ++i)
#pragma unroll
    for (int j = 0; j < 4; ++j) acc[i][j] = z4;

  const int srow = tid >> 3, sslot = tid & 7;
  const uint16_t* Ab = A + (size_t)bm * 128 * 1024;
  const uint16_t* Bb = Bw + (size_t)bn * 64 * 1024;

  for (int k0 = 0; k0 < 1024; k0 += 64) {
    __syncthreads();
#pragma unroll
    for (int is = 0; is < 4; ++is) {
      int row = is * 32 + srow;
      int gch = sslot ^ (row & 7);
      load_lds16(Ab + (size_t)row * 1024 + k0 + gch * 8,
                 (char*)sa + (is * 32 + w * 8) * 128);
    }
#pragma unroll
    for (int is = 0; is < 2; ++is) {
      int row = is * 32 + srow;
      int gch = sslot ^ (row & 7);
      load_lds16(Bb + (size_t)row * 1024 + k0 + gch * 8,
                 (char*)sb + (is * 32 + w * 8) * 128);
    }
    __syncthreads();
#pragma unroll
    for (int ks = 0; ks < 2; ++ks) {
      bf16x8 af[2], bfr[4];
#pragma unroll
      for (int i = 0; i < 2; ++i) {
        int ra = w * 32 + i * 16 + l16;
        af[i] = *reinterpret_cast<const bf16x8*>(sa + ra * 64 +
                                                 (((ks * 4 + q) ^ (ra & 7)) * 8));
      }
#pragma unroll
      for (int j = 0; j < 4; ++j) {
        int rb = j * 16 + l16;
        bfr[j] = *reinterpret_cast<const bf16x8*>(sb + rb * 64 +
                                                  (((ks * 4 + q) ^ (rb & 7)) * 8));
      }
#pragma unroll
      for (int i = 0; i < 2; ++i)
#pragma unroll
        for (int j = 0; j < 4; ++j)
          acc[i][j] =
              __builtin_amdgcn_mfma_f32_16x16x32_bf16(af[i], bfr[j], acc[i][j], 0, 0, 0);
    }
  }

#pragma unroll
  for (int i = 0; i < 2; ++i)
#pragma unroll
    for (int r = 0; r < 4; ++r) {
      int gm = bm * 128 + w * 32 + i * 16 + q * 4 + r;
#pragma unroll
      for (int j = 0; j < 4; ++j) {
        int gn = bn * 64 + j * 16 + l16;
        O[(size_t)gm * 1024 + gn] = acc[i][j][r];
      }
    }
}

// Flash attention, causal, exp2-domain softmax. Q,K: [b,s,h,d]; VT: [b,h,d,s];
// AO: [b,s,h,d] (all bf16). Block = 64 q-rows x (b,h); 4 waves x 16 rows.
// K-tiles of 64. grid (32, 32) = 1024 blocks.
__global__ __launch_bounds__(256) void flash_attn(const uint16_t* __restrict__ Q,
                                                  const uint16_t* __restrict__ K,
                                                  const uint16_t* __restrict__ VT,
                                                  uint16_t* __restrict__ AO) {
  __shared__ uint16_t ksm[64 * 64];     // 8 KiB
  __shared__ uint16_t vsm[64 * 64];     // 8 KiB
  __shared__ uint16_t psm[4][16 * 64];  // 8 KiB

  const int tid = threadIdx.x;
  const int lane = tid & 63, w = tid >> 6;
  const int q = lane >> 4, l16 = lane & 15;
  const int qt = 31 - blockIdx.x;  // heavy tiles first
  const int bh = blockIdx.y;
  const int b = bh >> 4, h = bh & 15;

  const size_t baseBS = (size_t)b * 2048 * 1024 + h * 64;
  const size_t baseVT = (size_t)bh * 64 * 2048;

  // Q fragments in registers (A-layout m=lane&15, k=quad*8+j)
  bf16x8 qf[2];
  const int r0 = qt * 64 + w * 16;
#pragma unroll
  for (int ks = 0; ks < 2; ++ks)
    qf[ks] = *reinterpret_cast<const bf16x8*>(
        Q + baseBS + (size_t)(r0 + l16) * 1024 + ks * 32 + q * 8);

  const f32x4 z4 = {0.f, 0.f, 0.f, 0.f};
  f32x4 oa[4];
#pragma unroll
  for (int di = 0; di < 4; ++di) oa[di] = z4;
  float m2[4], li[4];
#pragma unroll
  for (int r = 0; r < 4; ++r) { m2[r] = -1e30f; li[r] = 0.f; }

  const int srow = tid >> 3, sslot = tid & 7;
  const int nkt = qt + 1;
  const float SC = 0.18033688f;  // (1/8) * log2(e)

  for (int kt = 0; kt < nkt; ++kt) {
    __syncthreads();
#pragma unroll
    for (int is = 0; is < 2; ++is) {
      int row = is * 32 + srow;
      int gch = sslot ^ (row & 7);
      load_lds16(K + baseBS + (size_t)(kt * 64 + row) * 1024 + gch * 8,
                 (char*)ksm + (is * 32 + w * 8) * 128);
      load_lds16(VT + baseVT + (size_t)row * 2048 + kt * 64 + gch * 8,
                 (char*)vsm + (is * 32 + w * 8) * 128);
    }
    __syncthreads();

    // S = Q K^T (base-2 scaled)
    f32x4 sc[4];
#pragma unroll
    for (int nj = 0; nj < 4; ++nj) sc[nj] = z4;
#pragma unroll
    for (int ks = 0; ks < 2; ++ks) {
      bf16x8 kf[4];
#pragma unroll
      for (int nj = 0; nj < 4; ++nj) {
        int rk = nj * 16 + l16;
        kf[nj] = *reinterpret_cast<const bf16x8*>(ksm + rk * 64 +
                                                  (((ks * 4 + q) ^ (rk & 7)) * 8));
      }
#pragma unroll
      for (int nj = 0; nj < 4; ++nj)
        sc[nj] = __builtin_amdgcn_mfma_f32_16x16x32_bf16(qf[ks], kf[nj], sc[nj], 0, 0, 0);
    }

    if (kt == qt) {  // diagonal tile: causal mask
#pragma unroll
      for (int nj = 0; nj < 4; ++nj)
#pragma unroll
        for (int r = 0; r < 4; ++r) {
          int col = nj * 16 + l16;
          int row = w * 16 + q * 4 + r;
          sc[nj][r] = (col <= row) ? sc[nj][r] * SC : -1e30f;
        }
    } else {
#pragma unroll
      for (int nj = 0; nj < 4; ++nj)
#pragma unroll
        for (int r = 0; r < 4; ++r) sc[nj][r] *= SC;
    }

    // online softmax (base-2): row max over nj, then 16 lanes of the quad row
    float alpha[4], rs[4];
#pragma unroll
    for (int r = 0; r < 4; ++r) {
      float v = fmaxf(fmaxf(sc[0][r], sc[1][r]), fmaxf(sc[2][r], sc[3][r]));
      v = fmaxf(v, __shfl_xor(v, 1));
      v = fmaxf(v, __shfl_xor(v, 2));
      v = fmaxf(v, __shfl_xor(v, 4));
      v = fmaxf(v, __shfl_xor(v, 8));
      float mn = fmaxf(m2[r], v);
      alpha[r] = fexp2(m2[r] - mn);
      m2[r] = mn;
      rs[r] = 0.f;
    }

    // P = 2^(S - m); per-wave LDS round-trip in A-layout-friendly swizzle
#pragma unroll
    for (int nj = 0; nj < 4; ++nj)
#pragma unroll
      for (int r = 0; r < 4; ++r) {
        float p = fexp2(sc[nj][r] - m2[r]);
        rs[r] += p;
        int pr = q * 4 + r;
        int pc = nj * 16 + l16;
        psm[w][pr * 64 + (((pc >> 3) ^ (pr & 7)) * 8) + (pc & 7)] = f2bf(p);
      }

#pragma unroll
    for (int r = 0; r < 4; ++r) {
      float v = rs[r];
      v += __shfl_xor(v, 1);
      v += __shfl_xor(v, 2);
      v += __shfl_xor(v, 4);
      v += __shfl_xor(v, 8);
      li[r] = li[r] * alpha[r] + v;
    }

#pragma unroll
    for (int di = 0; di < 4; ++di)
#pragma unroll
      for (int r = 0; r < 4; ++r) oa[di][r] *= alpha[r];

    // O += P V (same-wave LDS RAW; compiler inserts lgkmcnt waits)
#pragma unroll
    for (int ks = 0; ks < 2; ++ks) {
      bf16x8 pf, vf[4];
      pf = *reinterpret_cast<const bf16x8*>(psm[w] + l16 * 64 +
                                            (((ks * 4 + q) ^ (l16 & 7)) * 8));
#pragma unroll
      for (int di = 0; di < 4; ++di) {
        int vr = di * 16 + l16;
        vf[di] = *reinterpret_cast<const bf16x8*>(vsm + vr * 64 +
                                                  (((ks * 4 + q) ^ (vr & 7)) * 8));
      }
#pragma unroll
      for (int di = 0; di < 4; ++di)
        oa[di] = __builtin_amdgcn_mfma_f32_16x16x32_bf16(pf, vf[di], oa[di], 0, 0, 0);
    }
  }

#pragma unroll
  for (int r = 0; r < 4; ++r) {
    float inv = 1.f / li[r];
    int gm = qt * 64 + w * 16 + q * 4 + r;
#pragma unroll
    for (int di = 0; di < 4; ++di)
      AO[baseBS + (size_t)gm * 1024 + di * 16 + l16] = f2bf(oa[di][r] * inv);
  }
}

extern "C" void kernel_launch(void* const* d_in, const int* in_sizes, int n_in,
                              void* d_out, int out_size, void* d_ws, size_t ws_size,
                              hipStream_t stream) {
  (void)in_sizes; (void)n_in; (void)out_size; (void)ws_size;
  const float* x = (const float*)d_in[0];
  const int* tokpos = (const int*)d_in[1];
  const float* wq = (const float*)d_in[2];
  const float* wk = (const float*)d_in[3];
  const float* wv = (const float*)d_in[4];
  const float* wo = (const float*)d_in[5];
  float* out = (float*)d_out;

  // workspace layout (bf16 elements): 48 MB total
  uint16_t* ws = (uint16_t*)d_ws;
  uint16_t* xb = ws;                   // 4096*1024
  uint16_t* wqb = xb + 4194304;        // wq|wk|wv|wo contiguous, 1M each
  uint16_t* wob = wqb + 3145728;
  uint16_t* Qb = wob + 1048576;        // [b,s,h,d]; Kb at +4194304
  uint16_t* VTb = Qb + 8388608;        // [b,h,d,s]
  uint16_t* AOb = VTb + 4194304;       // [b,s,h,d]

  cvt_all<<<8192, 256, 0, stream>>>(x, wq, wk, wv, wo, xb);

  gemm_qkv<<<dim3(24, 32), 256, 0, stream>>>(xb, wqb, Qb, VTb, tokpos);

  flash_attn<<<dim3(32, 32), 256, 0, stream>>>(Qb, Qb + 4194304, VTb, AOb);

  gemm_out<<<dim3(16, 32), 256, 0, stream>>>(AOb, wob, out);
}